// Round 13
// baseline (2513.428 us; speedup 1.0000x reference)
//
#include <hip/hip_runtime.h>
#include <hip/hip_bf16.h>
#include <math.h>

typedef __attribute__((ext_vector_type(8))) short bf16x8;
typedef __attribute__((ext_vector_type(4))) float f32x4;
typedef __attribute__((ext_vector_type(16))) float f32x16;
typedef __attribute__((ext_vector_type(4))) unsigned short ushort4v;

constexpr int Bsz = 16;

__device__ __forceinline__ float act_r(float v, int a) {
  if (a == 1) return v > 0.f ? v : 0.f;
  if (a == 2) return v >= 0.f ? v : 0.01f * v;
  return v;
}

__device__ __forceinline__ unsigned short f2bf(float x) {
  __hip_bfloat16 h = __float2bfloat16(x);   // RNE
  return __builtin_bit_cast(unsigned short, h);
}

// async global->LDS, 16B per lane; LDS dest must be wave-uniform base (+lane*16)
__device__ __forceinline__ void gll16(const unsigned short* g, unsigned short* l) {
  __builtin_amdgcn_global_load_lds(
      (const __attribute__((address_space(1))) unsigned int*)g,
      (__attribute__((address_space(3))) unsigned int*)l, 16, 0, 0);
}

// ---------------------------------------------------------------------------
// zprep: z1 f32 [16][192][16][16] -> bf16 [b][6][256 px][32 ic]
// ---------------------------------------------------------------------------
__global__ __launch_bounds__(256) void zprep_k(
    const float* __restrict__ z, unsigned short* __restrict__ zh)
{
  const int g = blockIdx.x * 256 + threadIdx.x;
  if (g >= 16 * 192 * 256) return;
  const int b  = g / 49152;
  const int rr = g - b * 49152;
  const int px = rr / 192;
  const int ic = rr - px * 192;
  const int o = ((b * 6 + (ic >> 5)) * 256 + px) * 32 + (ic & 31);
  zh[o] = f2bf(z[(b * 192 + ic) * 256 + px]);
}

// ---------------------------------------------------------------------------
// Weight preps (single bf16).  deconv src: [IC=192][OC][5][5];
// conv src: [OC][192][5][5].  deconv dst: bf16 [j 25][icb 24][oc][8 ic]
// ---------------------------------------------------------------------------
__device__ __forceinline__ void dprep_one(
    const float* __restrict__ w, unsigned short* __restrict__ wh, int OC, int g)
{
  const int oc  = g % OC;
  const int rem = g / OC;
  const int icb = rem % 24;
  const int j   = rem / 24;
  bf16x8 hv;
  #pragma unroll
  for (int e = 0; e < 8; ++e)
    hv[e] = (short)f2bf(w[((icb * 8 + e) * OC + oc) * 25 + j]);
  *(bf16x8*)&wh[((j * 24 + icb) * OC + oc) * 8] = hv;
}

__global__ __launch_bounds__(256) void wprep1_k(
    const float* __restrict__ s0, const float* __restrict__ s1,
    const float* __restrict__ s2, unsigned short* __restrict__ wh)
{
  const int bid = blockIdx.x;
  const int seg = bid / 450;
  const int g   = (bid - seg * 450) * 256 + threadIdx.x;
  if (g >= 192 * 24 * 25) return;
  const float* src = seg == 0 ? s0 : (seg == 1 ? s1 : s2);
  dprep_one(src, wh + (size_t)seg * 921600, 192, g);
}

__global__ __launch_bounds__(256) void wprep_d_k(
    const float* __restrict__ w, unsigned short* __restrict__ wh, int OC)
{
  const int g = blockIdx.x * 256 + threadIdx.x;
  if (g >= OC * 24 * 25) return;
  dprep_one(w, wh, OC, g);
}

// two 192-OC deconv weight preps in one launch (fewer dispatch gaps)
__global__ __launch_bounds__(256) void wprep_d2_k(
    const float* __restrict__ s0, const float* __restrict__ s1,
    unsigned short* __restrict__ wh)
{
  const int bid = blockIdx.x;
  const int seg = bid / 450;
  const int g   = (bid - seg * 450) * 256 + threadIdx.x;
  if (g >= 192 * 24 * 25) return;
  dprep_one(seg == 0 ? s0 : s1, wh + (size_t)seg * 921600, 192, g);
}

// conv3 weights, LANE-LINEAR 96-oc-block layout:
// W2[j][c6][ocb6][of6][lane64][8ic]; lane l = lg*16+ln holds
// icb = c*4+lg, oc = ocb*96 + of*16 + ln.  Each wave64 A-load is one
// contiguous 1KB segment (r9).  Total 2,764,800 ushorts (Wb slot).
__device__ __forceinline__ void tprep_one(
    const float* __restrict__ w, unsigned short* __restrict__ wh, int g)
{
  const int ln = g & 15;
  int r = g >> 4;
  const int lg  = r & 3;  r >>= 2;
  const int of  = r % 6;  r /= 6;
  const int ocb = r % 6;  r /= 6;
  const int c   = r % 6;  r /= 6;
  const int j   = r;                       // 0..24
  const int oc  = ocb * 96 + of * 16 + ln;
  const int icb = c * 4 + lg;
  bf16x8 hv;
  #pragma unroll
  for (int e = 0; e < 8; ++e)
    hv[e] = (short)f2bf(w[oc * 4800 + (icb * 8 + e) * 25 + j]);
  *(bf16x8*)&wh[(size_t)g * 8] = hv;
}

__global__ __launch_bounds__(256) void wprep_t_k(
    const float* __restrict__ w, unsigned short* __restrict__ wh)
{
  const int g = blockIdx.x * 256 + threadIdx.x;
  if (g >= 345600) return;
  tprep_one(w, wh, g);
}

// two conv3 weight preps in one launch
__global__ __launch_bounds__(256) void wprep_t2_k(
    const float* __restrict__ s0, const float* __restrict__ s1,
    unsigned short* __restrict__ wh)
{
  const int bid = blockIdx.x;
  const int seg = bid / 1350;
  const int g   = (bid - seg * 1350) * 256 + threadIdx.x;
  if (g >= 345600) return;
  tprep_one(seg == 0 ? s0 : s1, wh + (size_t)seg * 2764800, g);
}

// ---------------------------------------------------------------------------
// MFMA transposed conv k5 s2 p2 op1 (H x H -> 2H x 2H), single bf16, f32 acc.
// RPW input rows per wave (4*RPW per block), 32 oc per block.  Multi-branch
// via blockIdx.z = br*16 + b.  launch_bounds(256,3) -> clean round counts.
// Quarter-major LDS xs[row][q][PC][8]; one-time-zero halo; parity-preserving
// per-wave ky rotation; setprio on MFMA.
// OL=0: output [b][cg32][py][px][32ic]; OL=1: output [b][qg8][py][px][8ic].
// OMODE=2: per-tile max into mvp[b][TPB][OC], TPB = H/(4*RPW).
// ---------------------------------------------------------------------------
template<int H, int OMODE, int OL, int RPW>
__global__ __launch_bounds__(256, 3) void deconv2_k(
    const unsigned short* __restrict__ xh, long x_brs,
    const unsigned short* __restrict__ wh, long w_brs,
    const float* __restrict__ b0, const float* __restrict__ b1,
    const float* __restrict__ b2,
    unsigned short* __restrict__ yh, long y_brs,
    float* __restrict__ mvp, int OC, int a0, int a1, int a2)
{
  constexpr int NF = H / 16;
  constexpr int R  = 4 * RPW;               // input rows per block
  constexpr int PC = (H == 16) ? 20 : 36;   // padded cols
  constexpr int TPB = H / (4 * RPW);        // row-tiles per batch (OMODE=2)
  __shared__ __align__(16) unsigned short xs[R + 2][4][PC][8];
  __shared__ float red[4][32];

  const int zz = blockIdx.z;
  const int br = zz >> 4;
  const int b  = zz & 15;
  const int by = blockIdx.y;
  const int r0 = by * R;
  const int oc0 = blockIdx.x * 32;
  const int t  = threadIdx.x;
  const int wv = t >> 6;
  const int l  = t & 63;
  const int lg = l >> 4;
  const int ln = l & 15;

  const unsigned short* xhp = xh + (long)br * x_brs;
  const unsigned short* whp = wh + (long)br * w_brs;
  const float* bias = br == 0 ? b0 : (br == 1 ? b1 : b2);
  const int act = br == 0 ? a0 : (br == 1 ? a1 : a2);

  f32x4 acc[RPW][4][2][NF];
  #pragma unroll
  for (int rr = 0; rr < RPW; ++rr)
    #pragma unroll
    for (int p = 0; p < 4; ++p)
      #pragma unroll
      for (int of = 0; of < 2; ++of)
        #pragma unroll
        for (int nf = 0; nf < NF; ++nf)
          acc[rr][p][of][nf] = (f32x4){0.f, 0.f, 0.f, 0.f};

  // parity-preserving per-wave tap rotation: even kys {0,2,4} rotated by
  // wv%3, odd kys {1,3} by wv&1 -> p-class stays compile-time (rule 20)
  int evv[3], odv[2];
  {
    const int ev0[3] = {0, 2, 4};
    const int od0[2] = {1, 3};
    const int er = wv % 3, orr = wv & 1;
    #pragma unroll
    for (int i = 0; i < 3; ++i) { int ii = i + er; if (ii >= 3) ii -= 3; evv[i] = ev0[ii]; }
    #pragma unroll
    for (int i = 0; i < 2; ++i) { int ii = i + orr; if (ii >= 2) ii -= 2; odv[i] = od0[ii]; }
  }

  // one-time zero of the whole tile (halo cols + pad + OOB rows stay zero)
  {
    unsigned short* fx = (unsigned short*)xs;
    constexpr int ZL = (R + 2) * 4 * PC;
    const bf16x8 z8 = {0,0,0,0,0,0,0,0};
    #pragma unroll
    for (int k = 0; k < (ZL + 255) / 256; ++k) {
      const int li = t + k * 256;
      if (li < ZL) *(bf16x8*)&fx[li * 8] = z8;
    }
  }

  for (int c = 0; c < 6; ++c) {
    __syncthreads();
    constexpr int DC = (R + 2) * H * 4;
    #pragma unroll
    for (int k = 0; k < (DC + 255) / 256; ++k) {
      const int li = t + k * 256;
      if (li < DC) {
        const int part = li & 3;
        const int col  = (li >> 2) & (H - 1);
        const int row  = li / (4 * H);
        const int y    = r0 - 1 + row;
        if ((unsigned)y < (unsigned)H) {
          const bf16x8 v = *(const bf16x8*)&xhp[
              (((size_t)(b * 6 + c) * H + y) * H + col) * 32 + part * 8];
          *(bf16x8*)&xs[row][part][col + 1][0] = v;
        }
      }
    }
    __syncthreads();

    #define TAP_BODY(KY2, DY, P, KX)                                        \
      {                                                                     \
        const int jT = (KY2) * 5 + (KX);                                    \
        const int dxT = 1 - ((KX) >> 1);                                    \
        bf16x8 ahT[2];                                                      \
        const int wbaseT = ((jT * 24 + c * 4 + lg) * OC + oc0 + ln) * 8;    \
        _Pragma("unroll")                                                   \
        for (int of = 0; of < 2; ++of)                                      \
          ahT[of] = *(const bf16x8*)&whp[wbaseT + of * 128];                \
        _Pragma("unroll")                                                   \
        for (int rr = 0; rr < RPW; ++rr) {                                  \
          const int rlT = RPW * wv + rr + 1 + (DY);                         \
          bf16x8 bhT[NF];                                                   \
          _Pragma("unroll")                                                 \
          for (int nf = 0; nf < NF; ++nf)                                   \
            bhT[nf] = *(const bf16x8*)&xs[rlT][lg][1 + nf * 16 + ln + dxT][0]; \
          __builtin_amdgcn_s_setprio(1);                                    \
          _Pragma("unroll")                                                 \
          for (int of = 0; of < 2; ++of)                                    \
            _Pragma("unroll")                                               \
            for (int nf = 0; nf < NF; ++nf)                                 \
              acc[rr][P][of][nf] = __builtin_amdgcn_mfma_f32_16x16x32_bf16( \
                  ahT[of], bhT[nf], acc[rr][P][of][nf], 0, 0, 0);           \
          __builtin_amdgcn_s_setprio(0);                                    \
        }                                                                   \
      }

    #pragma unroll
    for (int ki = 0; ki < 3; ++ki) {      // even class: sy=0, p=sx
      const int ky2 = evv[ki];
      const int dy  = 1 - (ky2 >> 1);
      #pragma unroll
      for (int kx = 0; kx < 5; ++kx)
        TAP_BODY(ky2, dy, (kx & 1), kx)
    }
    #pragma unroll
    for (int ki = 0; ki < 2; ++ki) {      // odd class: sy=1, p=2+sx
      const int ky2 = odv[ki];
      const int dy  = 1 - (ky2 >> 1);
      #pragma unroll
      for (int kx = 0; kx < 5; ++kx)
        TAP_BODY(ky2, dy, (2 + (kx & 1)), kx)
    }
    #undef TAP_BODY
  }

  if (OMODE == 1) {
    const int OCG = OC >> 5;
    float bv[2][4];
    #pragma unroll
    for (int of = 0; of < 2; ++of)
      #pragma unroll
      for (int r = 0; r < 4; ++r)
        bv[of][r] = bias[oc0 + of * 16 + lg * 4 + r];
    unsigned short* yhp = yh + (long)br * y_brs;
    #pragma unroll
    for (int rr = 0; rr < RPW; ++rr) {
      const int iy = r0 + RPW * wv + rr;
      #pragma unroll
      for (int sy = 0; sy < 2; ++sy)
        #pragma unroll
        for (int sx = 0; sx < 2; ++sx) {
          const int p  = sy * 2 + sx;
          const int oy = 2 * iy + sy;
          #pragma unroll
          for (int of = 0; of < 2; ++of) {
            const int ocb = oc0 + of * 16 + lg * 4;
            const int cg  = ocb >> 5;
            const int co  = ocb & 31;
            #pragma unroll
            for (int nf = 0; nf < NF; ++nf) {
              const int ox = 2 * (nf * 16 + ln) + sx;
              ushort4v hv;
              #pragma unroll
              for (int r = 0; r < 4; ++r)
                hv[r] = f2bf(act_r(acc[rr][p][of][nf][r] + bv[of][r], act));
              size_t idx;
              if (OL) {
                const int qg = cg * 4 + (co >> 3);
                idx = (((size_t)(b * (OC >> 3) + qg) * (4 * H * H)) +
                       (size_t)oy * (2 * H) + ox) * 8 + (co & 7);
              } else {
                idx = (((size_t)(b * OCG + cg) * (4 * H * H)) +
                       (size_t)oy * (2 * H) + ox) * 32 + co;
              }
              *(ushort4v*)&yhp[idx] = hv;
            }
          }
        }
    }
  } else {
    #pragma unroll
    for (int of = 0; of < 2; ++of)
      #pragma unroll
      for (int r = 0; r < 4; ++r) {
        float m = -3.402823466e38f;
        #pragma unroll
        for (int rr = 0; rr < RPW; ++rr)
          #pragma unroll
          for (int p = 0; p < 4; ++p)
            #pragma unroll
            for (int nf = 0; nf < NF; ++nf)
              m = fmaxf(m, acc[rr][p][of][nf][r]);
        #pragma unroll
        for (int off = 1; off < 16; off <<= 1)
          m = fmaxf(m, __shfl_xor(m, off));
        if (ln == 0)
          red[wv][of * 16 + lg * 4 + r] = m + bias[oc0 + of * 16 + lg * 4 + r];
      }
    __syncthreads();
    if (t < 32) {
      const float v = fmaxf(fmaxf(red[0][t], red[1][t]), fmaxf(red[2][t], red[3][t]));
      mvp[((b * TPB) + by) * OC + oc0 + t] = v;
    }
  }
}

// ---------------------------------------------------------------------------
// Conv k5 s1 p2, 192 -> 576, 64x64.  mfma_f32_16x16x32, acc[6][4].
// r11 pipe arithmetic: LDS read port (12 waves x 100 ds_read_b128 x ~8cy
// ~= 10.3K cyc/CU/phase) exceeds MFMA pipe (5.8K) -> kernel was
// LDS-READ-BW-bound, explaining the 66% plateau + all scheduling nulls.
// This round: 96-oc wave tile (of=6): same 4 B ds_reads now feed 24 MFMAs
// (was 16) -> LDS-reads/MFMA x0.67, MFMA/SIMD/phase 8.7K vs LDS 10.3K.
// acc 96 + operands ~130 VGPR < 170 cap at (256,3); grid 1536x2 @ 768 =
// 4.0 clean rounds; XCD swizzle updated (1536 = 8x192).
// Bundle kept: pad-80 quarter-major LDS (0 conflicts), ky rotation,
// 2-slot pipeline + sched_barrier, setprio, gll staging, lane-linear W.
// X: [b][24 qg][64][64][8].  W2: [j][c6][ocb6][of6][lane64][8ic].
// ---------------------------------------------------------------------------
__global__ __launch_bounds__(256, 3) void conv3_k(
    const unsigned short* __restrict__ gxh, long x_brs,
    const unsigned short* __restrict__ gwh, long w_brs,
    const float* __restrict__ bias0, const float* __restrict__ bias1,
    float* __restrict__ out0, float* __restrict__ out1,
    int act0, int act1)
{
  __shared__ __align__(16) unsigned short xs[8][4][80][8];

  const int brz  = blockIdx.y;
  const unsigned short* gx = gxh + (long)brz * x_brs;
  const unsigned short* gw = gwh + (long)brz * w_brs;
  const float* bias = brz ? bias1 : bias0;
  float* out = brz ? out1 : out0;
  const int act = brz ? act1 : act0;

  const int bid  = blockIdx.x;
  const int orig = (bid & 7) * 192 + (bid >> 3);   // ocg-major chunks per XCD
  const int ocg  = orig >> 8;                      // 0..5 (96 oc each)
  const int rem  = orig & 255;
  const int b    = rem >> 4;
  const int band = rem & 15;
  const int y0   = band * 4;
  const int oc0  = ocg * 96;
  const int t    = threadIdx.x;
  const int wv   = t >> 6;
  const int l    = t & 63;
  const int lg   = l >> 4;      // ic 8-group (quarter) within the 32-ic phase
  const int ln   = l & 15;

  f32x4 acc[6][4];
  #pragma unroll
  for (int of = 0; of < 6; ++of)
    #pragma unroll
    for (int pf = 0; pf < 4; ++pf)
      acc[of][pf] = (f32x4){0.f, 0.f, 0.f, 0.f};

  // per-wave ky rotation (decorrelates the 4 waves' LDS row access + MFMA
  // phase); kx stays compile-time so bx offsets fold into ds immediates
  int ky2v[5], rlv[5];
  #pragma unroll
  for (int ky = 0; ky < 5; ++ky) {
    int k2 = ky + wv; if (k2 >= 5) k2 -= 5;
    ky2v[ky] = k2; rlv[ky] = wv + k2;
  }

  // one-time zero of the tile (covers halo cols + OOB rows; those cells are
  // never rewritten by the gll staging in any phase)
  {
    unsigned short* fx = (unsigned short*)xs;
    const bf16x8 z8 = {0,0,0,0,0,0,0,0};
    #pragma unroll
    for (int k = 0; k < 10; ++k) {
      const int li = t + k * 256;
      if (li < 2560) *(bf16x8*)&fx[li * 8] = z8;
    }
  }

  for (int c = 0; c < 6; ++c) {
    __syncthreads();   // prev compute done (and init-zero visible, c==0)
    // stage 8 rows x 4 quarters: 32 gll, 8 per wave; lane = column
    #pragma unroll
    for (int k = 0; k < 8; ++k) {
      const int idx = k * 4 + wv;
      const int row = idx >> 2, q = idx & 3;
      const int y = y0 - 2 + row;
      if ((unsigned)y < 64u) {
        const unsigned short* g = &gx[
            ((((size_t)b * 24 + c * 4 + q) << 12) + ((size_t)y << 6) + l) * 8];
        gll16(g, &xs[row][q][2][0]);
      }
    }
    __syncthreads();   // implicit vmcnt(0): staging visible

    // phase bases.  weight base: lane-linear layout, per-lane = l*16B
    const unsigned short* wrow =
        gw + (size_t)c * 18432 + (size_t)ocg * 3072 + (size_t)l * 8;
    const unsigned short* xrow[5];
    #pragma unroll
    for (int ky = 0; ky < 5; ++ky)
      xrow[ky] = &xs[rlv[ky]][lg][ln][0];

    bf16x8 ah[2][6], bx[2][4];

    // slot loader: ky,kx,slot all compile-time at call sites
    #define LDW(KY, KX, S)                                                  \
      {                                                                     \
        const unsigned short* wj = wrow + (size_t)(ky2v[KY] * 5 + (KX)) * 110592; \
        _Pragma("unroll")                                                   \
        for (int of = 0; of < 6; ++of)                                      \
          ah[S][of] = *(const bf16x8*)&wj[of * 512];                        \
        const unsigned short* xr = xrow[KY];                                \
        _Pragma("unroll")                                                   \
        for (int pf = 0; pf < 4; ++pf)                                      \
          bx[S][pf] = *(const bf16x8*)&xr[(pf * 16 + (KX)) * 8];            \
      }

    LDW(0, 0, 0)
    #pragma unroll
    for (int j = 0; j < 25; ++j) {
      const int s = j & 1;
      if (j < 24) {
        const int jn = j + 1;
        const int kyn = jn / 5, kxn = jn % 5;
        const int ns = jn & 1;
        LDW(kyn, kxn, ns)
      }
      __builtin_amdgcn_sched_barrier(0);
      __builtin_amdgcn_s_setprio(1);
      #pragma unroll
      for (int of = 0; of < 6; ++of)
        #pragma unroll
        for (int pf = 0; pf < 4; ++pf)
          acc[of][pf] = __builtin_amdgcn_mfma_f32_16x16x32_bf16(
              ah[s][of], bx[s][pf], acc[of][pf], 0, 0, 0);
      __builtin_amdgcn_s_setprio(0);
    }
    #undef LDW
  }

  // epilogue: D mapping (16x16): col = l&15 (px), row = (l>>4)*4 + r (oc)
  const int y = y0 + wv;
  #pragma unroll
  for (int of = 0; of < 6; ++of)
    #pragma unroll
    for (int r = 0; r < 4; ++r) {
      const int oc = oc0 + of * 16 + lg * 4 + r;
      const float bv = bias[oc];
      float* po = &out[(((size_t)(b * 576 + oc) * 64) + y) * 64 + ln];
      #pragma unroll
      for (int pf = 0; pf < 4; ++pf)
        po[16 * pf] = act_r(acc[of][pf][r] + bv, act);
    }
}

// ---------------------------------------------------------------------------
// Weights head: reduce 8 tile-maxes, leaky, 1x1 conv (576x576), softmax K=3
// ---------------------------------------------------------------------------
__global__ __launch_bounds__(256) void head_k(
    const float* __restrict__ mvp, const float* __restrict__ w3,
    const float* __restrict__ b3, float* __restrict__ outw)
{
  __shared__ float lv[576];
  __shared__ float yv[576];
  const int b = blockIdx.x;
  const int t = threadIdx.x;
  for (int i = t; i < 576; i += 256) {
    float m = mvp[(b * 8 + 0) * 576 + i];
    #pragma unroll
    for (int ti = 1; ti < 8; ++ti)
      m = fmaxf(m, mvp[(b * 8 + ti) * 576 + i]);
    lv[i] = m >= 0.f ? m : 0.01f * m;
  }
  __syncthreads();
  for (int oc = t; oc < 576; oc += 256) {
    float s = b3[oc];
    for (int c = 0; c < 576; ++c) s += w3[oc * 576 + c] * lv[c];
    yv[oc] = s;
  }
  __syncthreads();
  if (t < 192) {
    const float v0 = yv[t], v1 = yv[192 + t], v2 = yv[384 + t];
    const float mx = fmaxf(v0, fmaxf(v1, v2));
    const float e0 = expf(v0 - mx), e1 = expf(v1 - mx), e2 = expf(v2 - mx);
    const float inv = 1.f / (e0 + e1 + e2);
    outw[b * 576 + t]       = e0 * inv;
    outw[b * 576 + 192 + t] = e1 * inv;
    outw[b * 576 + 384 + t] = e2 * inv;
  }
}

extern "C" void kernel_launch(void* const* d_in, const int* in_sizes, int n_in,
                              void* d_out, int out_size, void* d_ws, size_t ws_size,
                              hipStream_t stream)
{
  (void)in_sizes; (void)n_in; (void)out_size;

  const float* z1    = (const float*)d_in[0];
  const float* gs_w1 = (const float*)d_in[1];
  const float* gs_b1 = (const float*)d_in[2];
  const float* gs_w2 = (const float*)d_in[3];
  const float* gs_b2 = (const float*)d_in[4];
  const float* gs_w3 = (const float*)d_in[5];
  const float* gs_b3 = (const float*)d_in[6];
  const float* gm_w1 = (const float*)d_in[7];
  const float* gm_b1 = (const float*)d_in[8];
  const float* gm_w2 = (const float*)d_in[9];
  const float* gm_b2 = (const float*)d_in[10];
  const float* gm_w3 = (const float*)d_in[11];
  const float* gm_b3 = (const float*)d_in[12];
  const float* gw_w1 = (const float*)d_in[13];
  const float* gw_b1 = (const float*)d_in[14];
  const float* gw_w2 = (const float*)d_in[15];
  const float* gw_b2 = (const float*)d_in[16];
  const float* gw_w3 = (const float*)d_in[17];
  const float* gw_b3 = (const float*)d_in[18];

  float* o_sigma = (float*)d_out;
  float* o_means = o_sigma + (size_t)Bsz * 576 * 64 * 64;
  float* o_w     = o_means + (size_t)Bsz * 576 * 64 * 64;

  dim3 blk(256);

  // merged layout needs ~87.7 MB workspace; fall back to sequential (~57 MB)
  const size_t NEED_MERGED = 87662592;   // bytes
  const bool merged = ws_size >= NEED_MERGED;

  if (merged) {
    // ushort units: Z 786432 | A1 3x3145728 | A2 2x12582912 |
    // Wd 2764800 | Wt 2x2764800 | MVp f32[16*8*576]
    unsigned short* p = (unsigned short*)d_ws;
    unsigned short* Z   = p; p += 786432;
    unsigned short* A1  = p; p += (size_t)3 * 3145728;
    unsigned short* A2  = p; p += (size_t)2 * 12582912;
    unsigned short* Wd  = p; p += 2764800;
    unsigned short* Wt  = p; p += (size_t)2 * 2764800;
    float* MVp = (float*)p;

    zprep_k<<<dim3(3072), blk, 0, stream>>>(z1, Z);
    wprep1_k<<<dim3(1350), blk, 0, stream>>>(gs_w1, gm_w1, gw_w1, Wd);

    // deconv1: 576 blocks @ 3/CU = single round
    deconv2_k<16,1,0,2><<<dim3(6,2,48), blk, 0, stream>>>(
        Z, 0, Wd, 921600, gs_b1, gm_b1, gw_b1,
        A1, 3145728, nullptr, 192, 1, 2, 2);

    // sigma+means deconv2, RPW=1: 1536 blocks @ 3/CU = 2.0 clean rounds
    wprep_d2_k<<<dim3(900), blk, 0, stream>>>(gs_w2, gm_w2, Wd);
    deconv2_k<32,1,1,1><<<dim3(6,8,32), blk, 0, stream>>>(
        A1, 3145728, Wd, 921600, gs_b2, gm_b2, gm_b2,
        A2, 12582912, nullptr, 192, 1, 2, 2);

    // sigma+means conv3 in ONE launch: 1536x2 @ 3/CU = 4.0 clean rounds
    wprep_t2_k<<<dim3(2700), blk, 0, stream>>>(gs_w3, gm_w3, Wt);
    conv3_k<<<dim3(1536, 2), blk, 0, stream>>>(
        A2, 12582912, Wt, 2764800, gs_b3, gm_b3, o_sigma, o_means, 1, 0);

    // weights branch, RPW=1: 2304 blocks @ 3/CU = 3.0 clean rounds
    wprep_d_k<<<dim3(1350), blk, 0, stream>>>(gw_w2, Wd, 576);
    deconv2_k<32,2,0,1><<<dim3(18,8,16), blk, 0, stream>>>(
        A1 + (size_t)2 * 3145728, 0, Wd, 0,
        gw_b2, gw_b2, gw_b2, nullptr, 0, MVp, 576, 0, 0, 0);
    head_k<<<dim3(16), blk, 0, stream>>>(MVp, gw_w3, gw_b3, o_w);
  } else {
    // fallback: sequential layout (~57 MB)
    unsigned short* p = (unsigned short*)d_ws;
    unsigned short* Z   = p; p += 786432;
    unsigned short* A1  = p; p += (size_t)3 * 3145728;
    unsigned short* A2  = p; p += 12582912;
    unsigned short* W1  = p; p += (size_t)3 * 921600;
    unsigned short* Wb  = p; p += 2764800;
    float* MVp = (float*)p;

    zprep_k<<<dim3(3072), blk, 0, stream>>>(z1, Z);
    wprep1_k<<<dim3(1350), blk, 0, stream>>>(gs_w1, gm_w1, gw_w1, W1);

    deconv2_k<16,1,0,2><<<dim3(6,2,48), blk, 0, stream>>>(
        Z, 0, W1, 921600, gs_b1, gm_b1, gw_b1,
        A1, 3145728, nullptr, 192, 1, 2, 2);

    // sigma branch
    wprep_d_k<<<dim3(450), blk, 0, stream>>>(gs_w2, Wb, 192);
    deconv2_k<32,1,1,1><<<dim3(6,8,16), blk, 0, stream>>>(
        A1, 0, Wb, 0, gs_b2, gs_b2, gs_b2,
        A2, 0, nullptr, 192, 1, 1, 1);
    wprep_t_k<<<dim3(1350), blk, 0, stream>>>(gs_w3, Wb);
    conv3_k<<<dim3(1536, 1), blk, 0, stream>>>(
        A2, 0, Wb, 0, gs_b3, gs_b3, o_sigma, o_sigma, 1, 1);

    // means branch
    wprep_d_k<<<dim3(450), blk, 0, stream>>>(gm_w2, Wb, 192);
    deconv2_k<32,1,1,1><<<dim3(6,8,16), blk, 0, stream>>>(
        A1 + (size_t)3145728, 0, Wb, 0, gm_b2, gm_b2, gm_b2,
        A2, 0, nullptr, 192, 2, 2, 2);
    wprep_t_k<<<dim3(1350), blk, 0, stream>>>(gm_w3, Wb);
    conv3_k<<<dim3(1536, 1), blk, 0, stream>>>(
        A2, 0, Wb, 0, gm_b3, gm_b3, o_means, o_means, 0, 0);

    // weights branch
    wprep_d_k<<<dim3(1350), blk, 0, stream>>>(gw_w2, Wb, 576);
    deconv2_k<32,2,0,1><<<dim3(18,8,16), blk, 0, stream>>>(
        A1 + (size_t)2 * 3145728, 0, Wb, 0,
        gw_b2, gw_b2, gw_b2, nullptr, 0, MVp, 576, 0, 0, 0);
    head_k<<<dim3(16), blk, 0, stream>>>(MVp, gw_w3, gw_b3, o_w);
  }
}

// Round 14
// 962.932 us; speedup vs baseline: 2.6102x; 2.6102x over previous
//
#include <hip/hip_runtime.h>
#include <hip/hip_bf16.h>
#include <math.h>

typedef __attribute__((ext_vector_type(8))) short bf16x8;
typedef __attribute__((ext_vector_type(4))) float f32x4;
typedef __attribute__((ext_vector_type(16))) float f32x16;
typedef __attribute__((ext_vector_type(4))) unsigned short ushort4v;

constexpr int Bsz = 16;

__device__ __forceinline__ float act_r(float v, int a) {
  if (a == 1) return v > 0.f ? v : 0.f;
  if (a == 2) return v >= 0.f ? v : 0.01f * v;
  return v;
}

__device__ __forceinline__ unsigned short f2bf(float x) {
  __hip_bfloat16 h = __float2bfloat16(x);   // RNE
  return __builtin_bit_cast(unsigned short, h);
}

// async global->LDS, 16B per lane; LDS dest must be wave-uniform base (+lane*16)
__device__ __forceinline__ void gll16(const unsigned short* g, unsigned short* l) {
  __builtin_amdgcn_global_load_lds(
      (const __attribute__((address_space(1))) unsigned int*)g,
      (__attribute__((address_space(3))) unsigned int*)l, 16, 0, 0);
}

// ---------------------------------------------------------------------------
// zprep: z1 f32 [16][192][16][16] -> bf16 [b][6][256 px][32 ic]
// ---------------------------------------------------------------------------
__global__ __launch_bounds__(256) void zprep_k(
    const float* __restrict__ z, unsigned short* __restrict__ zh)
{
  const int g = blockIdx.x * 256 + threadIdx.x;
  if (g >= 16 * 192 * 256) return;
  const int b  = g / 49152;
  const int rr = g - b * 49152;
  const int px = rr / 192;
  const int ic = rr - px * 192;
  const int o = ((b * 6 + (ic >> 5)) * 256 + px) * 32 + (ic & 31);
  zh[o] = f2bf(z[(b * 192 + ic) * 256 + px]);
}

// ---------------------------------------------------------------------------
// Weight preps (single bf16).  deconv src: [IC=192][OC][5][5];
// conv src: [OC][192][5][5].  deconv dst: bf16 [j 25][icb 24][oc][8 ic]
// ---------------------------------------------------------------------------
__device__ __forceinline__ void dprep_one(
    const float* __restrict__ w, unsigned short* __restrict__ wh, int OC, int g)
{
  const int oc  = g % OC;
  const int rem = g / OC;
  const int icb = rem % 24;
  const int j   = rem / 24;
  bf16x8 hv;
  #pragma unroll
  for (int e = 0; e < 8; ++e)
    hv[e] = (short)f2bf(w[((icb * 8 + e) * OC + oc) * 25 + j]);
  *(bf16x8*)&wh[((j * 24 + icb) * OC + oc) * 8] = hv;
}

__global__ __launch_bounds__(256) void wprep1_k(
    const float* __restrict__ s0, const float* __restrict__ s1,
    const float* __restrict__ s2, unsigned short* __restrict__ wh)
{
  const int bid = blockIdx.x;
  const int seg = bid / 450;
  const int g   = (bid - seg * 450) * 256 + threadIdx.x;
  if (g >= 192 * 24 * 25) return;
  const float* src = seg == 0 ? s0 : (seg == 1 ? s1 : s2);
  dprep_one(src, wh + (size_t)seg * 921600, 192, g);
}

__global__ __launch_bounds__(256) void wprep_d_k(
    const float* __restrict__ w, unsigned short* __restrict__ wh, int OC)
{
  const int g = blockIdx.x * 256 + threadIdx.x;
  if (g >= OC * 24 * 25) return;
  dprep_one(w, wh, OC, g);
}

// two 192-OC deconv weight preps in one launch (fewer dispatch gaps)
__global__ __launch_bounds__(256) void wprep_d2_k(
    const float* __restrict__ s0, const float* __restrict__ s1,
    unsigned short* __restrict__ wh)
{
  const int bid = blockIdx.x;
  const int seg = bid / 450;
  const int g   = (bid - seg * 450) * 256 + threadIdx.x;
  if (g >= 192 * 24 * 25) return;
  dprep_one(seg == 0 ? s0 : s1, wh + (size_t)seg * 921600, 192, g);
}

// conv3 weights, LANE-LINEAR 96-oc-block layout:
// W2[j][c6][ocb6][of6][lane64][8ic]; lane l = lg*16+ln holds
// icb = c*4+lg, oc = ocb*96 + of*16 + ln.  Each wave64 A-load is one
// contiguous 1KB segment (r9).  Total 2,764,800 ushorts (Wb slot).
// (correctness of this mapping verified by r12's passing absmax)
__device__ __forceinline__ void tprep_one(
    const float* __restrict__ w, unsigned short* __restrict__ wh, int g)
{
  const int ln = g & 15;
  int r = g >> 4;
  const int lg  = r & 3;  r >>= 2;
  const int of  = r % 6;  r /= 6;
  const int ocb = r % 6;  r /= 6;
  const int c   = r % 6;  r /= 6;
  const int j   = r;                       // 0..24
  const int oc  = ocb * 96 + of * 16 + ln;
  const int icb = c * 4 + lg;
  bf16x8 hv;
  #pragma unroll
  for (int e = 0; e < 8; ++e)
    hv[e] = (short)f2bf(w[oc * 4800 + (icb * 8 + e) * 25 + j]);
  *(bf16x8*)&wh[(size_t)g * 8] = hv;
}

__global__ __launch_bounds__(256) void wprep_t_k(
    const float* __restrict__ w, unsigned short* __restrict__ wh)
{
  const int g = blockIdx.x * 256 + threadIdx.x;
  if (g >= 345600) return;
  tprep_one(w, wh, g);
}

// two conv3 weight preps in one launch
__global__ __launch_bounds__(256) void wprep_t2_k(
    const float* __restrict__ s0, const float* __restrict__ s1,
    unsigned short* __restrict__ wh)
{
  const int bid = blockIdx.x;
  const int seg = bid / 1350;
  const int g   = (bid - seg * 1350) * 256 + threadIdx.x;
  if (g >= 345600) return;
  tprep_one(seg == 0 ? s0 : s1, wh + (size_t)seg * 2764800, g);
}

// ---------------------------------------------------------------------------
// MFMA transposed conv k5 s2 p2 op1 (H x H -> 2H x 2H), single bf16, f32 acc.
// RPW input rows per wave (4*RPW per block), 32 oc per block.  Multi-branch
// via blockIdx.z = br*16 + b.  launch_bounds(256,3) -> clean round counts.
// Quarter-major LDS xs[row][q][PC][8]; one-time-zero halo; parity-preserving
// per-wave ky rotation; setprio on MFMA.
// OL=0: output [b][cg32][py][px][32ic]; OL=1: output [b][qg8][py][px][8ic].
// OMODE=2: per-tile max into mvp[b][TPB][OC], TPB = H/(4*RPW).
// ---------------------------------------------------------------------------
template<int H, int OMODE, int OL, int RPW>
__global__ __launch_bounds__(256, 3) void deconv2_k(
    const unsigned short* __restrict__ xh, long x_brs,
    const unsigned short* __restrict__ wh, long w_brs,
    const float* __restrict__ b0, const float* __restrict__ b1,
    const float* __restrict__ b2,
    unsigned short* __restrict__ yh, long y_brs,
    float* __restrict__ mvp, int OC, int a0, int a1, int a2)
{
  constexpr int NF = H / 16;
  constexpr int R  = 4 * RPW;               // input rows per block
  constexpr int PC = (H == 16) ? 20 : 36;   // padded cols
  constexpr int TPB = H / (4 * RPW);        // row-tiles per batch (OMODE=2)
  __shared__ __align__(16) unsigned short xs[R + 2][4][PC][8];
  __shared__ float red[4][32];

  const int zz = blockIdx.z;
  const int br = zz >> 4;
  const int b  = zz & 15;
  const int by = blockIdx.y;
  const int r0 = by * R;
  const int oc0 = blockIdx.x * 32;
  const int t  = threadIdx.x;
  const int wv = t >> 6;
  const int l  = t & 63;
  const int lg = l >> 4;
  const int ln = l & 15;

  const unsigned short* xhp = xh + (long)br * x_brs;
  const unsigned short* whp = wh + (long)br * w_brs;
  const float* bias = br == 0 ? b0 : (br == 1 ? b1 : b2);
  const int act = br == 0 ? a0 : (br == 1 ? a1 : a2);

  f32x4 acc[RPW][4][2][NF];
  #pragma unroll
  for (int rr = 0; rr < RPW; ++rr)
    #pragma unroll
    for (int p = 0; p < 4; ++p)
      #pragma unroll
      for (int of = 0; of < 2; ++of)
        #pragma unroll
        for (int nf = 0; nf < NF; ++nf)
          acc[rr][p][of][nf] = (f32x4){0.f, 0.f, 0.f, 0.f};

  // parity-preserving per-wave tap rotation: even kys {0,2,4} rotated by
  // wv%3, odd kys {1,3} by wv&1 -> p-class stays compile-time (rule 20)
  int evv[3], odv[2];
  {
    const int ev0[3] = {0, 2, 4};
    const int od0[2] = {1, 3};
    const int er = wv % 3, orr = wv & 1;
    #pragma unroll
    for (int i = 0; i < 3; ++i) { int ii = i + er; if (ii >= 3) ii -= 3; evv[i] = ev0[ii]; }
    #pragma unroll
    for (int i = 0; i < 2; ++i) { int ii = i + orr; if (ii >= 2) ii -= 2; odv[i] = od0[ii]; }
  }

  // one-time zero of the whole tile (halo cols + pad + OOB rows stay zero)
  {
    unsigned short* fx = (unsigned short*)xs;
    constexpr int ZL = (R + 2) * 4 * PC;
    const bf16x8 z8 = {0,0,0,0,0,0,0,0};
    #pragma unroll
    for (int k = 0; k < (ZL + 255) / 256; ++k) {
      const int li = t + k * 256;
      if (li < ZL) *(bf16x8*)&fx[li * 8] = z8;
    }
  }

  for (int c = 0; c < 6; ++c) {
    __syncthreads();
    constexpr int DC = (R + 2) * H * 4;
    #pragma unroll
    for (int k = 0; k < (DC + 255) / 256; ++k) {
      const int li = t + k * 256;
      if (li < DC) {
        const int part = li & 3;
        const int col  = (li >> 2) & (H - 1);
        const int row  = li / (4 * H);
        const int y    = r0 - 1 + row;
        if ((unsigned)y < (unsigned)H) {
          const bf16x8 v = *(const bf16x8*)&xhp[
              (((size_t)(b * 6 + c) * H + y) * H + col) * 32 + part * 8];
          *(bf16x8*)&xs[row][part][col + 1][0] = v;
        }
      }
    }
    __syncthreads();

    #define TAP_BODY(KY2, DY, P, KX)                                        \
      {                                                                     \
        const int jT = (KY2) * 5 + (KX);                                    \
        const int dxT = 1 - ((KX) >> 1);                                    \
        bf16x8 ahT[2];                                                      \
        const int wbaseT = ((jT * 24 + c * 4 + lg) * OC + oc0 + ln) * 8;    \
        _Pragma("unroll")                                                   \
        for (int of = 0; of < 2; ++of)                                      \
          ahT[of] = *(const bf16x8*)&whp[wbaseT + of * 128];                \
        _Pragma("unroll")                                                   \
        for (int rr = 0; rr < RPW; ++rr) {                                  \
          const int rlT = RPW * wv + rr + 1 + (DY);                         \
          bf16x8 bhT[NF];                                                   \
          _Pragma("unroll")                                                 \
          for (int nf = 0; nf < NF; ++nf)                                   \
            bhT[nf] = *(const bf16x8*)&xs[rlT][lg][1 + nf * 16 + ln + dxT][0]; \
          __builtin_amdgcn_s_setprio(1);                                    \
          _Pragma("unroll")                                                 \
          for (int of = 0; of < 2; ++of)                                    \
            _Pragma("unroll")                                               \
            for (int nf = 0; nf < NF; ++nf)                                 \
              acc[rr][P][of][nf] = __builtin_amdgcn_mfma_f32_16x16x32_bf16( \
                  ahT[of], bhT[nf], acc[rr][P][of][nf], 0, 0, 0);           \
          __builtin_amdgcn_s_setprio(0);                                    \
        }                                                                   \
      }

    #pragma unroll
    for (int ki = 0; ki < 3; ++ki) {      // even class: sy=0, p=sx
      const int ky2 = evv[ki];
      const int dy  = 1 - (ky2 >> 1);
      #pragma unroll
      for (int kx = 0; kx < 5; ++kx)
        TAP_BODY(ky2, dy, (kx & 1), kx)
    }
    #pragma unroll
    for (int ki = 0; ki < 2; ++ki) {      // odd class: sy=1, p=2+sx
      const int ky2 = odv[ki];
      const int dy  = 1 - (ky2 >> 1);
      #pragma unroll
      for (int kx = 0; kx < 5; ++kx)
        TAP_BODY(ky2, dy, (2 + (kx & 1)), kx)
    }
    #undef TAP_BODY
  }

  if (OMODE == 1) {
    const int OCG = OC >> 5;
    float bv[2][4];
    #pragma unroll
    for (int of = 0; of < 2; ++of)
      #pragma unroll
      for (int r = 0; r < 4; ++r)
        bv[of][r] = bias[oc0 + of * 16 + lg * 4 + r];
    unsigned short* yhp = yh + (long)br * y_brs;
    #pragma unroll
    for (int rr = 0; rr < RPW; ++rr) {
      const int iy = r0 + RPW * wv + rr;
      #pragma unroll
      for (int sy = 0; sy < 2; ++sy)
        #pragma unroll
        for (int sx = 0; sx < 2; ++sx) {
          const int p  = sy * 2 + sx;
          const int oy = 2 * iy + sy;
          #pragma unroll
          for (int of = 0; of < 2; ++of) {
            const int ocb = oc0 + of * 16 + lg * 4;
            const int cg  = ocb >> 5;
            const int co  = ocb & 31;
            #pragma unroll
            for (int nf = 0; nf < NF; ++nf) {
              const int ox = 2 * (nf * 16 + ln) + sx;
              ushort4v hv;
              #pragma unroll
              for (int r = 0; r < 4; ++r)
                hv[r] = f2bf(act_r(acc[rr][p][of][nf][r] + bv[of][r], act));
              size_t idx;
              if (OL) {
                const int qg = cg * 4 + (co >> 3);
                idx = (((size_t)(b * (OC >> 3) + qg) * (4 * H * H)) +
                       (size_t)oy * (2 * H) + ox) * 8 + (co & 7);
              } else {
                idx = (((size_t)(b * OCG + cg) * (4 * H * H)) +
                       (size_t)oy * (2 * H) + ox) * 32 + co;
              }
              *(ushort4v*)&yhp[idx] = hv;
            }
          }
        }
    }
  } else {
    #pragma unroll
    for (int of = 0; of < 2; ++of)
      #pragma unroll
      for (int r = 0; r < 4; ++r) {
        float m = -3.402823466e38f;
        #pragma unroll
        for (int rr = 0; rr < RPW; ++rr)
          #pragma unroll
          for (int p = 0; p < 4; ++p)
            #pragma unroll
            for (int nf = 0; nf < NF; ++nf)
              m = fmaxf(m, acc[rr][p][of][nf][r]);
        #pragma unroll
        for (int off = 1; off < 16; off <<= 1)
          m = fmaxf(m, __shfl_xor(m, off));
        if (ln == 0)
          red[wv][of * 16 + lg * 4 + r] = m + bias[oc0 + of * 16 + lg * 4 + r];
      }
    __syncthreads();
    if (t < 32) {
      const float v = fmaxf(fmaxf(red[0][t], red[1][t]), fmaxf(red[2][t], red[3][t]));
      mvp[((b * TPB) + by) * OC + oc0 + t] = v;
    }
  }
}

// ---------------------------------------------------------------------------
// Conv k5 s1 p2, 192 -> 576, 64x64.  mfma_f32_16x16x32, acc[6][4].
// r12 SPILLED: acc 96 + 2-slot operands 80 + addr > 170-reg cap at (256,3)
// -> scratch (WRITE_SIZE 313MB -> 5.1GB).  Fix: SINGLE-slot operands
// (ah[6]+bx[4] = 40 regs; 96+40+addr ~= 161 < 170).  The 2-slot pipeline
// and sched_barrier were proven null in r7/r8 (compiler self-schedules),
// so dropping them is free.  LDS-BW theory (r11 arithmetic: LDS read port
// 10.3K cyc/CU/phase vs MFMA 5.8K at of=4; of=6 -> 8.7K vs 10.3K) now
// gets a clean test at register parity.
// Bundle: pad-80 quarter-major LDS (0 conflicts), ky rotation, setprio,
// gll staging, (256,3), XCD swizzle (1536 = 8x192), lane-linear weights.
// X: [b][24 qg][64][64][8].  W2: [j][c6][ocb6][of6][lane64][8ic].
// ---------------------------------------------------------------------------
__global__ __launch_bounds__(256, 3) void conv3_k(
    const unsigned short* __restrict__ gxh, long x_brs,
    const unsigned short* __restrict__ gwh, long w_brs,
    const float* __restrict__ bias0, const float* __restrict__ bias1,
    float* __restrict__ out0, float* __restrict__ out1,
    int act0, int act1)
{
  __shared__ __align__(16) unsigned short xs[8][4][80][8];

  const int brz  = blockIdx.y;
  const unsigned short* gx = gxh + (long)brz * x_brs;
  const unsigned short* gw = gwh + (long)brz * w_brs;
  const float* bias = brz ? bias1 : bias0;
  float* out = brz ? out1 : out0;
  const int act = brz ? act1 : act0;

  const int bid  = blockIdx.x;
  const int orig = (bid & 7) * 192 + (bid >> 3);   // ocg-major chunks per XCD
  const int ocg  = orig >> 8;                      // 0..5 (96 oc each)
  const int rem  = orig & 255;
  const int b    = rem >> 4;
  const int band = rem & 15;
  const int y0   = band * 4;
  const int oc0  = ocg * 96;
  const int t    = threadIdx.x;
  const int wv   = t >> 6;
  const int l    = t & 63;
  const int lg   = l >> 4;      // ic 8-group (quarter) within the 32-ic phase
  const int ln   = l & 15;

  f32x4 acc[6][4];
  #pragma unroll
  for (int of = 0; of < 6; ++of)
    #pragma unroll
    for (int pf = 0; pf < 4; ++pf)
      acc[of][pf] = (f32x4){0.f, 0.f, 0.f, 0.f};

  // per-wave ky rotation (decorrelates the 4 waves' LDS row access + MFMA
  // phase); kx stays compile-time so bx offsets fold into ds immediates
  int ky2v[5], rlv[5];
  #pragma unroll
  for (int ky = 0; ky < 5; ++ky) {
    int k2 = ky + wv; if (k2 >= 5) k2 -= 5;
    ky2v[ky] = k2; rlv[ky] = wv + k2;
  }

  // one-time zero of the tile (covers halo cols + OOB rows; those cells are
  // never rewritten by the gll staging in any phase)
  {
    unsigned short* fx = (unsigned short*)xs;
    const bf16x8 z8 = {0,0,0,0,0,0,0,0};
    #pragma unroll
    for (int k = 0; k < 10; ++k) {
      const int li = t + k * 256;
      if (li < 2560) *(bf16x8*)&fx[li * 8] = z8;
    }
  }

  for (int c = 0; c < 6; ++c) {
    __syncthreads();   // prev compute done (and init-zero visible, c==0)
    // stage 8 rows x 4 quarters: 32 gll, 8 per wave; lane = column
    #pragma unroll
    for (int k = 0; k < 8; ++k) {
      const int idx = k * 4 + wv;
      const int row = idx >> 2, q = idx & 3;
      const int y = y0 - 2 + row;
      if ((unsigned)y < 64u) {
        const unsigned short* g = &gx[
            ((((size_t)b * 24 + c * 4 + q) << 12) + ((size_t)y << 6) + l) * 8];
        gll16(g, &xs[row][q][2][0]);
      }
    }
    __syncthreads();   // implicit vmcnt(0): staging visible

    // phase bases.  weight base: lane-linear layout, per-lane = l*16B
    const unsigned short* wrow =
        gw + (size_t)c * 18432 + (size_t)ocg * 3072 + (size_t)l * 8;
    const unsigned short* xrow[5];
    #pragma unroll
    for (int ky = 0; ky < 5; ++ky)
      xrow[ky] = &xs[rlv[ky]][lg][ln][0];

    // single-slot operands (register-parity fix for the r12 spill);
    // j fully unrolled -> compiler software-pipelines across iterations
    #pragma unroll
    for (int j = 0; j < 25; ++j) {
      const int ky = j / 5, kx = j % 5;
      bf16x8 ah[6], bx[4];
      const unsigned short* wj = wrow + (size_t)(ky2v[ky] * 5 + kx) * 110592;
      #pragma unroll
      for (int of = 0; of < 6; ++of)
        ah[of] = *(const bf16x8*)&wj[of * 512];
      const unsigned short* xr = xrow[ky];
      #pragma unroll
      for (int pf = 0; pf < 4; ++pf)
        bx[pf] = *(const bf16x8*)&xr[(pf * 16 + kx) * 8];
      __builtin_amdgcn_s_setprio(1);
      #pragma unroll
      for (int of = 0; of < 6; ++of)
        #pragma unroll
        for (int pf = 0; pf < 4; ++pf)
          acc[of][pf] = __builtin_amdgcn_mfma_f32_16x16x32_bf16(
              ah[of], bx[pf], acc[of][pf], 0, 0, 0);
      __builtin_amdgcn_s_setprio(0);
    }
  }

  // epilogue: D mapping (16x16): col = l&15 (px), row = (l>>4)*4 + r (oc)
  const int y = y0 + wv;
  #pragma unroll
  for (int of = 0; of < 6; ++of)
    #pragma unroll
    for (int r = 0; r < 4; ++r) {
      const int oc = oc0 + of * 16 + lg * 4 + r;
      const float bv = bias[oc];
      float* po = &out[(((size_t)(b * 576 + oc) * 64) + y) * 64 + ln];
      #pragma unroll
      for (int pf = 0; pf < 4; ++pf)
        po[16 * pf] = act_r(acc[of][pf][r] + bv, act);
    }
}

// ---------------------------------------------------------------------------
// Weights head: reduce 8 tile-maxes, leaky, 1x1 conv (576x576), softmax K=3
// ---------------------------------------------------------------------------
__global__ __launch_bounds__(256) void head_k(
    const float* __restrict__ mvp, const float* __restrict__ w3,
    const float* __restrict__ b3, float* __restrict__ outw)
{
  __shared__ float lv[576];
  __shared__ float yv[576];
  const int b = blockIdx.x;
  const int t = threadIdx.x;
  for (int i = t; i < 576; i += 256) {
    float m = mvp[(b * 8 + 0) * 576 + i];
    #pragma unroll
    for (int ti = 1; ti < 8; ++ti)
      m = fmaxf(m, mvp[(b * 8 + ti) * 576 + i]);
    lv[i] = m >= 0.f ? m : 0.01f * m;
  }
  __syncthreads();
  for (int oc = t; oc < 576; oc += 256) {
    float s = b3[oc];
    for (int c = 0; c < 576; ++c) s += w3[oc * 576 + c] * lv[c];
    yv[oc] = s;
  }
  __syncthreads();
  if (t < 192) {
    const float v0 = yv[t], v1 = yv[192 + t], v2 = yv[384 + t];
    const float mx = fmaxf(v0, fmaxf(v1, v2));
    const float e0 = expf(v0 - mx), e1 = expf(v1 - mx), e2 = expf(v2 - mx);
    const float inv = 1.f / (e0 + e1 + e2);
    outw[b * 576 + t]       = e0 * inv;
    outw[b * 576 + 192 + t] = e1 * inv;
    outw[b * 576 + 384 + t] = e2 * inv;
  }
}

extern "C" void kernel_launch(void* const* d_in, const int* in_sizes, int n_in,
                              void* d_out, int out_size, void* d_ws, size_t ws_size,
                              hipStream_t stream)
{
  (void)in_sizes; (void)n_in; (void)out_size;

  const float* z1    = (const float*)d_in[0];
  const float* gs_w1 = (const float*)d_in[1];
  const float* gs_b1 = (const float*)d_in[2];
  const float* gs_w2 = (const float*)d_in[3];
  const float* gs_b2 = (const float*)d_in[4];
  const float* gs_w3 = (const float*)d_in[5];
  const float* gs_b3 = (const float*)d_in[6];
  const float* gm_w1 = (const float*)d_in[7];
  const float* gm_b1 = (const float*)d_in[8];
  const float* gm_w2 = (const float*)d_in[9];
  const float* gm_b2 = (const float*)d_in[10];
  const float* gm_w3 = (const float*)d_in[11];
  const float* gm_b3 = (const float*)d_in[12];
  const float* gw_w1 = (const float*)d_in[13];
  const float* gw_b1 = (const float*)d_in[14];
  const float* gw_w2 = (const float*)d_in[15];
  const float* gw_b2 = (const float*)d_in[16];
  const float* gw_w3 = (const float*)d_in[17];
  const float* gw_b3 = (const float*)d_in[18];

  float* o_sigma = (float*)d_out;
  float* o_means = o_sigma + (size_t)Bsz * 576 * 64 * 64;
  float* o_w     = o_means + (size_t)Bsz * 576 * 64 * 64;

  dim3 blk(256);

  // merged layout needs ~87.7 MB workspace; fall back to sequential (~57 MB)
  const size_t NEED_MERGED = 87662592;   // bytes
  const bool merged = ws_size >= NEED_MERGED;

  if (merged) {
    // ushort units: Z 786432 | A1 3x3145728 | A2 2x12582912 |
    // Wd 2764800 | Wt 2x2764800 | MVp f32[16*8*576]
    unsigned short* p = (unsigned short*)d_ws;
    unsigned short* Z   = p; p += 786432;
    unsigned short* A1  = p; p += (size_t)3 * 3145728;
    unsigned short* A2  = p; p += (size_t)2 * 12582912;
    unsigned short* Wd  = p; p += 2764800;
    unsigned short* Wt  = p; p += (size_t)2 * 2764800;
    float* MVp = (float*)p;

    zprep_k<<<dim3(3072), blk, 0, stream>>>(z1, Z);
    wprep1_k<<<dim3(1350), blk, 0, stream>>>(gs_w1, gm_w1, gw_w1, Wd);

    // deconv1: 576 blocks @ 3/CU = single round
    deconv2_k<16,1,0,2><<<dim3(6,2,48), blk, 0, stream>>>(
        Z, 0, Wd, 921600, gs_b1, gm_b1, gw_b1,
        A1, 3145728, nullptr, 192, 1, 2, 2);

    // sigma+means deconv2, RPW=1: 1536 blocks @ 3/CU = 2.0 clean rounds
    wprep_d2_k<<<dim3(900), blk, 0, stream>>>(gs_w2, gm_w2, Wd);
    deconv2_k<32,1,1,1><<<dim3(6,8,32), blk, 0, stream>>>(
        A1, 3145728, Wd, 921600, gs_b2, gm_b2, gm_b2,
        A2, 12582912, nullptr, 192, 1, 2, 2);

    // sigma+means conv3 in ONE launch: 1536x2 @ 3/CU = 4.0 clean rounds
    wprep_t2_k<<<dim3(2700), blk, 0, stream>>>(gs_w3, gm_w3, Wt);
    conv3_k<<<dim3(1536, 2), blk, 0, stream>>>(
        A2, 12582912, Wt, 2764800, gs_b3, gm_b3, o_sigma, o_means, 1, 0);

    // weights branch, RPW=1: 2304 blocks @ 3/CU = 3.0 clean rounds
    wprep_d_k<<<dim3(1350), blk, 0, stream>>>(gw_w2, Wd, 576);
    deconv2_k<32,2,0,1><<<dim3(18,8,16), blk, 0, stream>>>(
        A1 + (size_t)2 * 3145728, 0, Wd, 0,
        gw_b2, gw_b2, gw_b2, nullptr, 0, MVp, 576, 0, 0, 0);
    head_k<<<dim3(16), blk, 0, stream>>>(MVp, gw_w3, gw_b3, o_w);
  } else {
    // fallback: sequential layout (~57 MB)
    unsigned short* p = (unsigned short*)d_ws;
    unsigned short* Z   = p; p += 786432;
    unsigned short* A1  = p; p += (size_t)3 * 3145728;
    unsigned short* A2  = p; p += 12582912;
    unsigned short* W1  = p; p += (size_t)3 * 921600;
    unsigned short* Wb  = p; p += 2764800;
    float* MVp = (float*)p;

    zprep_k<<<dim3(3072), blk, 0, stream>>>(z1, Z);
    wprep1_k<<<dim3(1350), blk, 0, stream>>>(gs_w1, gm_w1, gw_w1, W1);

    deconv2_k<16,1,0,2><<<dim3(6,2,48), blk, 0, stream>>>(
        Z, 0, W1, 921600, gs_b1, gm_b1, gw_b1,
        A1, 3145728, nullptr, 192, 1, 2, 2);

    // sigma branch
    wprep_d_k<<<dim3(450), blk, 0, stream>>>(gs_w2, Wb, 192);
    deconv2_k<32,1,1,1><<<dim3(6,8,16), blk, 0, stream>>>(
        A1, 0, Wb, 0, gs_b2, gs_b2, gs_b2,
        A2, 0, nullptr, 192, 1, 1, 1);
    wprep_t_k<<<dim3(1350), blk, 0, stream>>>(gs_w3, Wb);
    conv3_k<<<dim3(1536, 1), blk, 0, stream>>>(
        A2, 0, Wb, 0, gs_b3, gs_b3, o_sigma, o_sigma, 1, 1);

    // means branch
    wprep_d_k<<<dim3(450), blk, 0, stream>>>(gm_w2, Wb, 192);
    deconv2_k<32,1,1,1><<<dim3(6,8,16), blk, 0, stream>>>(
        A1 + (size_t)3145728, 0, Wb, 0, gm_b2, gm_b2, gm_b2,
        A2, 0, nullptr, 192, 2, 2, 2);
    wprep_t_k<<<dim3(1350), blk, 0, stream>>>(gm_w3, Wb);
    conv3_k<<<dim3(1536, 1), blk, 0, stream>>>(
        A2, 0, Wb, 0, gm_b3, gm_b3, o_means, o_means, 0, 0);

    // weights branch
    wprep_d_k<<<dim3(1350), blk, 0, stream>>>(gw_w2, Wb, 576);
    deconv2_k<32,2,0,1><<<dim3(18,8,16), blk, 0, stream>>>(
        A1 + (size_t)2 * 3145728, 0, Wb, 0,
        gw_b2, gw_b2, gw_b2, nullptr, 0, MVp, 576, 0, 0, 0);
    head_k<<<dim3(16), blk, 0, stream>>>(MVp, gw_w3, gw_b3, o_w);
  }
}

// Round 15
// 956.570 us; speedup vs baseline: 2.6275x; 1.0067x over previous
//
#include <hip/hip_runtime.h>
#include <hip/hip_bf16.h>
#include <math.h>

typedef __attribute__((ext_vector_type(8))) short bf16x8;
typedef __attribute__((ext_vector_type(4))) float f32x4;
typedef __attribute__((ext_vector_type(16))) float f32x16;
typedef __attribute__((ext_vector_type(4))) unsigned short ushort4v;

constexpr int Bsz = 16;

__device__ __forceinline__ float act_r(float v, int a) {
  if (a == 1) return v > 0.f ? v : 0.f;
  if (a == 2) return v >= 0.f ? v : 0.01f * v;
  return v;
}

__device__ __forceinline__ unsigned short f2bf(float x) {
  __hip_bfloat16 h = __float2bfloat16(x);   // RNE
  return __builtin_bit_cast(unsigned short, h);
}

// async global->LDS, 16B per lane; LDS dest must be wave-uniform base (+lane*16)
__device__ __forceinline__ void gll16(const unsigned short* g, unsigned short* l) {
  __builtin_amdgcn_global_load_lds(
      (const __attribute__((address_space(1))) unsigned int*)g,
      (__attribute__((address_space(3))) unsigned int*)l, 16, 0, 0);
}

// ---------------------------------------------------------------------------
// zprep: z1 f32 [16][192][16][16] -> bf16 [b][6][256 px][32 ic]
// ---------------------------------------------------------------------------
__global__ __launch_bounds__(256) void zprep_k(
    const float* __restrict__ z, unsigned short* __restrict__ zh)
{
  const int g = blockIdx.x * 256 + threadIdx.x;
  if (g >= 16 * 192 * 256) return;
  const int b  = g / 49152;
  const int rr = g - b * 49152;
  const int px = rr / 192;
  const int ic = rr - px * 192;
  const int o = ((b * 6 + (ic >> 5)) * 256 + px) * 32 + (ic & 31);
  zh[o] = f2bf(z[(b * 192 + ic) * 256 + px]);
}

// ---------------------------------------------------------------------------
// Weight preps (single bf16).  deconv src: [IC=192][OC][5][5];
// conv src: [OC][192][5][5].  deconv dst: bf16 [j 25][icb 24][oc][8 ic]
// ---------------------------------------------------------------------------
__device__ __forceinline__ void dprep_one(
    const float* __restrict__ w, unsigned short* __restrict__ wh, int OC, int g)
{
  const int oc  = g % OC;
  const int rem = g / OC;
  const int icb = rem % 24;
  const int j   = rem / 24;
  bf16x8 hv;
  #pragma unroll
  for (int e = 0; e < 8; ++e)
    hv[e] = (short)f2bf(w[((icb * 8 + e) * OC + oc) * 25 + j]);
  *(bf16x8*)&wh[((j * 24 + icb) * OC + oc) * 8] = hv;
}

__global__ __launch_bounds__(256) void wprep1_k(
    const float* __restrict__ s0, const float* __restrict__ s1,
    const float* __restrict__ s2, unsigned short* __restrict__ wh)
{
  const int bid = blockIdx.x;
  const int seg = bid / 450;
  const int g   = (bid - seg * 450) * 256 + threadIdx.x;
  if (g >= 192 * 24 * 25) return;
  const float* src = seg == 0 ? s0 : (seg == 1 ? s1 : s2);
  dprep_one(src, wh + (size_t)seg * 921600, 192, g);
}

__global__ __launch_bounds__(256) void wprep_d_k(
    const float* __restrict__ w, unsigned short* __restrict__ wh, int OC)
{
  const int g = blockIdx.x * 256 + threadIdx.x;
  if (g >= OC * 24 * 25) return;
  dprep_one(w, wh, OC, g);
}

// two 192-OC deconv weight preps in one launch (fewer dispatch gaps)
__global__ __launch_bounds__(256) void wprep_d2_k(
    const float* __restrict__ s0, const float* __restrict__ s1,
    unsigned short* __restrict__ wh)
{
  const int bid = blockIdx.x;
  const int seg = bid / 450;
  const int g   = (bid - seg * 450) * 256 + threadIdx.x;
  if (g >= 192 * 24 * 25) return;
  dprep_one(seg == 0 ? s0 : s1, wh + (size_t)seg * 921600, 192, g);
}

// conv3 weights, LANE-LINEAR layout (r9/r11 banked version):
// W2[j][c6][ocb9][of4][lane64][8ic]; lane l = lg*16+ln holds
// icb = c*4+lg, oc = ocb*64 + of*16 + ln.  Each wave64 A-load is one
// contiguous 1KB segment.  Total 2,764,800 ushorts (Wb slot).
__device__ __forceinline__ void tprep_one(
    const float* __restrict__ w, unsigned short* __restrict__ wh, int g)
{
  const int ln = g & 15;
  int r = g >> 4;
  const int lg  = r & 3;  r >>= 2;
  const int of  = r & 3;  r >>= 2;
  const int ocb = r % 9;  r /= 9;
  const int c   = r % 6;  r /= 6;
  const int j   = r;                       // 0..24
  const int oc  = ocb * 64 + of * 16 + ln;
  const int icb = c * 4 + lg;
  bf16x8 hv;
  #pragma unroll
  for (int e = 0; e < 8; ++e)
    hv[e] = (short)f2bf(w[oc * 4800 + (icb * 8 + e) * 25 + j]);
  *(bf16x8*)&wh[(size_t)g * 8] = hv;
}

__global__ __launch_bounds__(256) void wprep_t_k(
    const float* __restrict__ w, unsigned short* __restrict__ wh)
{
  const int g = blockIdx.x * 256 + threadIdx.x;
  if (g >= 345600) return;
  tprep_one(w, wh, g);
}

// two conv3 weight preps in one launch
__global__ __launch_bounds__(256) void wprep_t2_k(
    const float* __restrict__ s0, const float* __restrict__ s1,
    unsigned short* __restrict__ wh)
{
  const int bid = blockIdx.x;
  const int seg = bid / 1350;
  const int g   = (bid - seg * 1350) * 256 + threadIdx.x;
  if (g >= 345600) return;
  tprep_one(seg == 0 ? s0 : s1, wh + (size_t)seg * 2764800, g);
}

// ---------------------------------------------------------------------------
// MFMA transposed conv k5 s2 p2 op1 (H x H -> 2H x 2H), single bf16, f32 acc.
// RPW input rows per wave (4*RPW per block), 32 oc per block.  Multi-branch
// via blockIdx.z = br*16 + b.  launch_bounds(256,3) -> clean round counts.
// Quarter-major LDS xs[row][q][PC][8]; one-time-zero halo; parity-preserving
// per-wave ky rotation; setprio on MFMA.
// OL=0: output [b][cg32][py][px][32ic]; OL=1: output [b][qg8][py][px][8ic].
// OMODE=2: per-tile max into mvp[b][TPB][OC], TPB = H/(4*RPW).
// ---------------------------------------------------------------------------
template<int H, int OMODE, int OL, int RPW>
__global__ __launch_bounds__(256, 3) void deconv2_k(
    const unsigned short* __restrict__ xh, long x_brs,
    const unsigned short* __restrict__ wh, long w_brs,
    const float* __restrict__ b0, const float* __restrict__ b1,
    const float* __restrict__ b2,
    unsigned short* __restrict__ yh, long y_brs,
    float* __restrict__ mvp, int OC, int a0, int a1, int a2)
{
  constexpr int NF = H / 16;
  constexpr int R  = 4 * RPW;               // input rows per block
  constexpr int PC = (H == 16) ? 20 : 36;   // padded cols
  constexpr int TPB = H / (4 * RPW);        // row-tiles per batch (OMODE=2)
  __shared__ __align__(16) unsigned short xs[R + 2][4][PC][8];
  __shared__ float red[4][32];

  const int zz = blockIdx.z;
  const int br = zz >> 4;
  const int b  = zz & 15;
  const int by = blockIdx.y;
  const int r0 = by * R;
  const int oc0 = blockIdx.x * 32;
  const int t  = threadIdx.x;
  const int wv = t >> 6;
  const int l  = t & 63;
  const int lg = l >> 4;
  const int ln = l & 15;

  const unsigned short* xhp = xh + (long)br * x_brs;
  const unsigned short* whp = wh + (long)br * w_brs;
  const float* bias = br == 0 ? b0 : (br == 1 ? b1 : b2);
  const int act = br == 0 ? a0 : (br == 1 ? a1 : a2);

  f32x4 acc[RPW][4][2][NF];
  #pragma unroll
  for (int rr = 0; rr < RPW; ++rr)
    #pragma unroll
    for (int p = 0; p < 4; ++p)
      #pragma unroll
      for (int of = 0; of < 2; ++of)
        #pragma unroll
        for (int nf = 0; nf < NF; ++nf)
          acc[rr][p][of][nf] = (f32x4){0.f, 0.f, 0.f, 0.f};

  // parity-preserving per-wave tap rotation: even kys {0,2,4} rotated by
  // wv%3, odd kys {1,3} by wv&1 -> p-class stays compile-time (rule 20)
  int evv[3], odv[2];
  {
    const int ev0[3] = {0, 2, 4};
    const int od0[2] = {1, 3};
    const int er = wv % 3, orr = wv & 1;
    #pragma unroll
    for (int i = 0; i < 3; ++i) { int ii = i + er; if (ii >= 3) ii -= 3; evv[i] = ev0[ii]; }
    #pragma unroll
    for (int i = 0; i < 2; ++i) { int ii = i + orr; if (ii >= 2) ii -= 2; odv[i] = od0[ii]; }
  }

  // one-time zero of the whole tile (halo cols + pad + OOB rows stay zero)
  {
    unsigned short* fx = (unsigned short*)xs;
    constexpr int ZL = (R + 2) * 4 * PC;
    const bf16x8 z8 = {0,0,0,0,0,0,0,0};
    #pragma unroll
    for (int k = 0; k < (ZL + 255) / 256; ++k) {
      const int li = t + k * 256;
      if (li < ZL) *(bf16x8*)&fx[li * 8] = z8;
    }
  }

  for (int c = 0; c < 6; ++c) {
    __syncthreads();
    constexpr int DC = (R + 2) * H * 4;
    #pragma unroll
    for (int k = 0; k < (DC + 255) / 256; ++k) {
      const int li = t + k * 256;
      if (li < DC) {
        const int part = li & 3;
        const int col  = (li >> 2) & (H - 1);
        const int row  = li / (4 * H);
        const int y    = r0 - 1 + row;
        if ((unsigned)y < (unsigned)H) {
          const bf16x8 v = *(const bf16x8*)&xhp[
              (((size_t)(b * 6 + c) * H + y) * H + col) * 32 + part * 8];
          *(bf16x8*)&xs[row][part][col + 1][0] = v;
        }
      }
    }
    __syncthreads();

    #define TAP_BODY(KY2, DY, P, KX)                                        \
      {                                                                     \
        const int jT = (KY2) * 5 + (KX);                                    \
        const int dxT = 1 - ((KX) >> 1);                                    \
        bf16x8 ahT[2];                                                      \
        const int wbaseT = ((jT * 24 + c * 4 + lg) * OC + oc0 + ln) * 8;    \
        _Pragma("unroll")                                                   \
        for (int of = 0; of < 2; ++of)                                      \
          ahT[of] = *(const bf16x8*)&whp[wbaseT + of * 128];                \
        _Pragma("unroll")                                                   \
        for (int rr = 0; rr < RPW; ++rr) {                                  \
          const int rlT = RPW * wv + rr + 1 + (DY);                         \
          bf16x8 bhT[NF];                                                   \
          _Pragma("unroll")                                                 \
          for (int nf = 0; nf < NF; ++nf)                                   \
            bhT[nf] = *(const bf16x8*)&xs[rlT][lg][1 + nf * 16 + ln + dxT][0]; \
          __builtin_amdgcn_s_setprio(1);                                    \
          _Pragma("unroll")                                                 \
          for (int of = 0; of < 2; ++of)                                    \
            _Pragma("unroll")                                               \
            for (int nf = 0; nf < NF; ++nf)                                 \
              acc[rr][P][of][nf] = __builtin_amdgcn_mfma_f32_16x16x32_bf16( \
                  ahT[of], bhT[nf], acc[rr][P][of][nf], 0, 0, 0);           \
          __builtin_amdgcn_s_setprio(0);                                    \
        }                                                                   \
      }

    #pragma unroll
    for (int ki = 0; ki < 3; ++ki) {      // even class: sy=0, p=sx
      const int ky2 = evv[ki];
      const int dy  = 1 - (ky2 >> 1);
      #pragma unroll
      for (int kx = 0; kx < 5; ++kx)
        TAP_BODY(ky2, dy, (kx & 1), kx)
    }
    #pragma unroll
    for (int ki = 0; ki < 2; ++ki) {      // odd class: sy=1, p=2+sx
      const int ky2 = odv[ki];
      const int dy  = 1 - (ky2 >> 1);
      #pragma unroll
      for (int kx = 0; kx < 5; ++kx)
        TAP_BODY(ky2, dy, (2 + (kx & 1)), kx)
    }
    #undef TAP_BODY
  }

  if (OMODE == 1) {
    const int OCG = OC >> 5;
    float bv[2][4];
    #pragma unroll
    for (int of = 0; of < 2; ++of)
      #pragma unroll
      for (int r = 0; r < 4; ++r)
        bv[of][r] = bias[oc0 + of * 16 + lg * 4 + r];
    unsigned short* yhp = yh + (long)br * y_brs;
    #pragma unroll
    for (int rr = 0; rr < RPW; ++rr) {
      const int iy = r0 + RPW * wv + rr;
      #pragma unroll
      for (int sy = 0; sy < 2; ++sy)
        #pragma unroll
        for (int sx = 0; sx < 2; ++sx) {
          const int p  = sy * 2 + sx;
          const int oy = 2 * iy + sy;
          #pragma unroll
          for (int of = 0; of < 2; ++of) {
            const int ocb = oc0 + of * 16 + lg * 4;
            const int cg  = ocb >> 5;
            const int co  = ocb & 31;
            #pragma unroll
            for (int nf = 0; nf < NF; ++nf) {
              const int ox = 2 * (nf * 16 + ln) + sx;
              ushort4v hv;
              #pragma unroll
              for (int r = 0; r < 4; ++r)
                hv[r] = f2bf(act_r(acc[rr][p][of][nf][r] + bv[of][r], act));
              size_t idx;
              if (OL) {
                const int qg = cg * 4 + (co >> 3);
                idx = (((size_t)(b * (OC >> 3) + qg) * (4 * H * H)) +
                       (size_t)oy * (2 * H) + ox) * 8 + (co & 7);
              } else {
                idx = (((size_t)(b * OCG + cg) * (4 * H * H)) +
                       (size_t)oy * (2 * H) + ox) * 32 + co;
              }
              *(ushort4v*)&yhp[idx] = hv;
            }
          }
        }
    }
  } else {
    #pragma unroll
    for (int of = 0; of < 2; ++of)
      #pragma unroll
      for (int r = 0; r < 4; ++r) {
        float m = -3.402823466e38f;
        #pragma unroll
        for (int rr = 0; rr < RPW; ++rr)
          #pragma unroll
          for (int p = 0; p < 4; ++p)
            #pragma unroll
            for (int nf = 0; nf < NF; ++nf)
              m = fmaxf(m, acc[rr][p][of][nf][r]);
        #pragma unroll
        for (int off = 1; off < 16; off <<= 1)
          m = fmaxf(m, __shfl_xor(m, off));
        if (ln == 0)
          red[wv][of * 16 + lg * 4 + r] = m + bias[oc0 + of * 16 + lg * 4 + r];
      }
    __syncthreads();
    if (t < 32) {
      const float v = fmaxf(fmaxf(red[0][t], red[1][t]), fmaxf(red[2][t], red[3][t]));
      mvp[((b * TPB) + by) * OC + oc0 + t] = v;
    }
  }
}

// ---------------------------------------------------------------------------
// Conv k5 s1 p2, 192 -> 576, 64x64.  mfma_f32_16x16x32, acc[4][4].
// REVERTED to the r11-banked of=4 kernel (543us merged / MfmaUtil 66.6%)
// after the of=6 A/B falsified the LDS-BW theory at register parity
// (r12 spilled: 2290us; r13 parity: 564us / 61.6% -- both lose to of=4).
// Theory ledger exhausted: MFMA shape (r6), occupancy (r2), pipelining
// (r7/r8 null), TA addressing (r9, +2%, kept), LDS-BW ratio (r12/r13).
// 66.6% MfmaUtil > m201 plain-HIP GEMM reference (62.1%).
// Bundle: pad-80 quarter-major LDS (0 conflicts), ky rotation, 2-slot
// LDW + sched_barrier, setprio, gll staging, (256,3), XCD swizzle (x288),
// lane-linear weights.  2-branch merge via blockIdx.y.
// X: [b][24 qg][64][64][8].  W2: [j][c6][ocb9][of4][lane64][8ic].
// ---------------------------------------------------------------------------
__global__ __launch_bounds__(256, 3) void conv3_k(
    const unsigned short* __restrict__ gxh, long x_brs,
    const unsigned short* __restrict__ gwh, long w_brs,
    const float* __restrict__ bias0, const float* __restrict__ bias1,
    float* __restrict__ out0, float* __restrict__ out1,
    int act0, int act1)
{
  __shared__ __align__(16) unsigned short xs[8][4][80][8];

  const int brz  = blockIdx.y;
  const unsigned short* gx = gxh + (long)brz * x_brs;
  const unsigned short* gw = gwh + (long)brz * w_brs;
  const float* bias = brz ? bias1 : bias0;
  float* out = brz ? out1 : out0;
  const int act = brz ? act1 : act0;

  const int bid  = blockIdx.x;
  const int orig = (bid & 7) * 288 + (bid >> 3);   // ocg-major chunks per XCD
  const int ocg  = orig >> 8;
  const int rem  = orig & 255;
  const int b    = rem >> 4;
  const int band = rem & 15;
  const int y0   = band * 4;
  const int oc0  = ocg * 64;
  const int t    = threadIdx.x;
  const int wv   = t >> 6;
  const int l    = t & 63;
  const int lg   = l >> 4;      // ic 8-group (quarter) within the 32-ic phase
  const int ln   = l & 15;

  f32x4 acc[4][4];
  #pragma unroll
  for (int of = 0; of < 4; ++of)
    #pragma unroll
    for (int pf = 0; pf < 4; ++pf)
      acc[of][pf] = (f32x4){0.f, 0.f, 0.f, 0.f};

  // per-wave ky rotation (decorrelates the 4 waves' LDS row access + MFMA
  // phase); kx stays compile-time so bx offsets fold into ds immediates
  int ky2v[5], rlv[5];
  #pragma unroll
  for (int ky = 0; ky < 5; ++ky) {
    int k2 = ky + wv; if (k2 >= 5) k2 -= 5;
    ky2v[ky] = k2; rlv[ky] = wv + k2;
  }

  // one-time zero of the tile (covers halo cols + OOB rows; those cells are
  // never rewritten by the gll staging in any phase)
  {
    unsigned short* fx = (unsigned short*)xs;
    const bf16x8 z8 = {0,0,0,0,0,0,0,0};
    #pragma unroll
    for (int k = 0; k < 10; ++k) {
      const int li = t + k * 256;
      if (li < 2560) *(bf16x8*)&fx[li * 8] = z8;
    }
  }

  for (int c = 0; c < 6; ++c) {
    __syncthreads();   // prev compute done (and init-zero visible, c==0)
    // stage 8 rows x 4 quarters: 32 gll, 8 per wave; lane = column
    #pragma unroll
    for (int k = 0; k < 8; ++k) {
      const int idx = k * 4 + wv;
      const int row = idx >> 2, q = idx & 3;
      const int y = y0 - 2 + row;
      if ((unsigned)y < 64u) {
        const unsigned short* g = &gx[
            ((((size_t)b * 24 + c * 4 + q) << 12) + ((size_t)y << 6) + l) * 8];
        gll16(g, &xs[row][q][2][0]);
      }
    }
    __syncthreads();   // implicit vmcnt(0): staging visible

    // phase bases.  weight base: lane-linear layout, per-lane = l*16B
    const unsigned short* wrow =
        gw + (size_t)c * 18432 + (size_t)ocg * 2048 + (size_t)l * 8;
    const unsigned short* xrow[5];
    #pragma unroll
    for (int ky = 0; ky < 5; ++ky)
      xrow[ky] = &xs[rlv[ky]][lg][ln][0];

    bf16x8 ah[2][4], bx[2][4];

    // slot loader: ky,kx,slot all compile-time at call sites
    #define LDW(KY, KX, S)                                                  \
      {                                                                     \
        const unsigned short* wj = wrow + (size_t)(ky2v[KY] * 5 + (KX)) * 110592; \
        _Pragma("unroll")                                                   \
        for (int of = 0; of < 4; ++of)                                      \
          ah[S][of] = *(const bf16x8*)&wj[of * 512];                        \
        const unsigned short* xr = xrow[KY];                                \
        _Pragma("unroll")                                                   \
        for (int pf = 0; pf < 4; ++pf)                                      \
          bx[S][pf] = *(const bf16x8*)&xr[(pf * 16 + (KX)) * 8];            \
      }

    LDW(0, 0, 0)
    #pragma unroll
    for (int j = 0; j < 25; ++j) {
      const int s = j & 1;
      if (j < 24) {
        const int jn = j + 1;
        const int kyn = jn / 5, kxn = jn % 5;
        const int ns = jn & 1;
        LDW(kyn, kxn, ns)
      }
      __builtin_amdgcn_sched_barrier(0);
      __builtin_amdgcn_s_setprio(1);
      #pragma unroll
      for (int of = 0; of < 4; ++of)
        #pragma unroll
        for (int pf = 0; pf < 4; ++pf)
          acc[of][pf] = __builtin_amdgcn_mfma_f32_16x16x32_bf16(
              ah[s][of], bx[s][pf], acc[of][pf], 0, 0, 0);
      __builtin_amdgcn_s_setprio(0);
    }
    #undef LDW
  }

  // epilogue: D mapping (16x16): col = l&15 (px), row = (l>>4)*4 + r (oc)
  const int y = y0 + wv;
  #pragma unroll
  for (int of = 0; of < 4; ++of)
    #pragma unroll
    for (int r = 0; r < 4; ++r) {
      const int oc = oc0 + of * 16 + lg * 4 + r;
      const float bv = bias[oc];
      float* po = &out[(((size_t)(b * 576 + oc) * 64) + y) * 64 + ln];
      #pragma unroll
      for (int pf = 0; pf < 4; ++pf)
        po[16 * pf] = act_r(acc[of][pf][r] + bv, act);
    }
}

// ---------------------------------------------------------------------------
// Weights head: reduce 8 tile-maxes, leaky, 1x1 conv (576x576), softmax K=3
// ---------------------------------------------------------------------------
__global__ __launch_bounds__(256) void head_k(
    const float* __restrict__ mvp, const float* __restrict__ w3,
    const float* __restrict__ b3, float* __restrict__ outw)
{
  __shared__ float lv[576];
  __shared__ float yv[576];
  const int b = blockIdx.x;
  const int t = threadIdx.x;
  for (int i = t; i < 576; i += 256) {
    float m = mvp[(b * 8 + 0) * 576 + i];
    #pragma unroll
    for (int ti = 1; ti < 8; ++ti)
      m = fmaxf(m, mvp[(b * 8 + ti) * 576 + i]);
    lv[i] = m >= 0.f ? m : 0.01f * m;
  }
  __syncthreads();
  for (int oc = t; oc < 576; oc += 256) {
    float s = b3[oc];
    for (int c = 0; c < 576; ++c) s += w3[oc * 576 + c] * lv[c];
    yv[oc] = s;
  }
  __syncthreads();
  if (t < 192) {
    const float v0 = yv[t], v1 = yv[192 + t], v2 = yv[384 + t];
    const float mx = fmaxf(v0, fmaxf(v1, v2));
    const float e0 = expf(v0 - mx), e1 = expf(v1 - mx), e2 = expf(v2 - mx);
    const float inv = 1.f / (e0 + e1 + e2);
    outw[b * 576 + t]       = e0 * inv;
    outw[b * 576 + 192 + t] = e1 * inv;
    outw[b * 576 + 384 + t] = e2 * inv;
  }
}

extern "C" void kernel_launch(void* const* d_in, const int* in_sizes, int n_in,
                              void* d_out, int out_size, void* d_ws, size_t ws_size,
                              hipStream_t stream)
{
  (void)in_sizes; (void)n_in; (void)out_size;

  const float* z1    = (const float*)d_in[0];
  const float* gs_w1 = (const float*)d_in[1];
  const float* gs_b1 = (const float*)d_in[2];
  const float* gs_w2 = (const float*)d_in[3];
  const float* gs_b2 = (const float*)d_in[4];
  const float* gs_w3 = (const float*)d_in[5];
  const float* gs_b3 = (const float*)d_in[6];
  const float* gm_w1 = (const float*)d_in[7];
  const float* gm_b1 = (const float*)d_in[8];
  const float* gm_w2 = (const float*)d_in[9];
  const float* gm_b2 = (const float*)d_in[10];
  const float* gm_w3 = (const float*)d_in[11];
  const float* gm_b3 = (const float*)d_in[12];
  const float* gw_w1 = (const float*)d_in[13];
  const float* gw_b1 = (const float*)d_in[14];
  const float* gw_w2 = (const float*)d_in[15];
  const float* gw_b2 = (const float*)d_in[16];
  const float* gw_w3 = (const float*)d_in[17];
  const float* gw_b3 = (const float*)d_in[18];

  float* o_sigma = (float*)d_out;
  float* o_means = o_sigma + (size_t)Bsz * 576 * 64 * 64;
  float* o_w     = o_means + (size_t)Bsz * 576 * 64 * 64;

  dim3 blk(256);

  // merged layout needs ~87.7 MB workspace; fall back to sequential (~57 MB)
  const size_t NEED_MERGED = 87662592;   // bytes
  const bool merged = ws_size >= NEED_MERGED;

  if (merged) {
    // ushort units: Z 786432 | A1 3x3145728 | A2 2x12582912 |
    // Wd 2764800 | Wt 2x2764800 | MVp f32[16*8*576]
    unsigned short* p = (unsigned short*)d_ws;
    unsigned short* Z   = p; p += 786432;
    unsigned short* A1  = p; p += (size_t)3 * 3145728;
    unsigned short* A2  = p; p += (size_t)2 * 12582912;
    unsigned short* Wd  = p; p += 2764800;
    unsigned short* Wt  = p; p += (size_t)2 * 2764800;
    float* MVp = (float*)p;

    zprep_k<<<dim3(3072), blk, 0, stream>>>(z1, Z);
    wprep1_k<<<dim3(1350), blk, 0, stream>>>(gs_w1, gm_w1, gw_w1, Wd);

    // deconv1: 576 blocks @ 3/CU = single round
    deconv2_k<16,1,0,2><<<dim3(6,2,48), blk, 0, stream>>>(
        Z, 0, Wd, 921600, gs_b1, gm_b1, gw_b1,
        A1, 3145728, nullptr, 192, 1, 2, 2);

    // sigma+means deconv2, RPW=1: 1536 blocks @ 3/CU = 2.0 clean rounds
    wprep_d2_k<<<dim3(900), blk, 0, stream>>>(gs_w2, gm_w2, Wd);
    deconv2_k<32,1,1,1><<<dim3(6,8,32), blk, 0, stream>>>(
        A1, 3145728, Wd, 921600, gs_b2, gm_b2, gm_b2,
        A2, 12582912, nullptr, 192, 1, 2, 2);

    // sigma+means conv3 in ONE 4608-block launch (6.0 clean rounds @3/CU)
    wprep_t2_k<<<dim3(2700), blk, 0, stream>>>(gs_w3, gm_w3, Wt);
    conv3_k<<<dim3(2304, 2), blk, 0, stream>>>(
        A2, 12582912, Wt, 2764800, gs_b3, gm_b3, o_sigma, o_means, 1, 0);

    // weights branch, RPW=1: 2304 blocks @ 3/CU = 3.0 clean rounds
    wprep_d_k<<<dim3(1350), blk, 0, stream>>>(gw_w2, Wd, 576);
    deconv2_k<32,2,0,1><<<dim3(18,8,16), blk, 0, stream>>>(
        A1 + (size_t)2 * 3145728, 0, Wd, 0,
        gw_b2, gw_b2, gw_b2, nullptr, 0, MVp, 576, 0, 0, 0);
    head_k<<<dim3(16), blk, 0, stream>>>(MVp, gw_w3, gw_b3, o_w);
  } else {
    // fallback: sequential layout (~57 MB)
    unsigned short* p = (unsigned short*)d_ws;
    unsigned short* Z   = p; p += 786432;
    unsigned short* A1  = p; p += (size_t)3 * 3145728;
    unsigned short* A2  = p; p += 12582912;
    unsigned short* W1  = p; p += (size_t)3 * 921600;
    unsigned short* Wb  = p; p += 2764800;
    float* MVp = (float*)p;

    zprep_k<<<dim3(3072), blk, 0, stream>>>(z1, Z);
    wprep1_k<<<dim3(1350), blk, 0, stream>>>(gs_w1, gm_w1, gw_w1, W1);

    deconv2_k<16,1,0,2><<<dim3(6,2,48), blk, 0, stream>>>(
        Z, 0, W1, 921600, gs_b1, gm_b1, gw_b1,
        A1, 3145728, nullptr, 192, 1, 2, 2);

    // sigma branch
    wprep_d_k<<<dim3(450), blk, 0, stream>>>(gs_w2, Wb, 192);
    deconv2_k<32,1,1,1><<<dim3(6,8,16), blk, 0, stream>>>(
        A1, 0, Wb, 0, gs_b2, gs_b2, gs_b2,
        A2, 0, nullptr, 192, 1, 1, 1);
    wprep_t_k<<<dim3(1350), blk, 0, stream>>>(gs_w3, Wb);
    conv3_k<<<dim3(2304, 1), blk, 0, stream>>>(
        A2, 0, Wb, 0, gs_b3, gs_b3, o_sigma, o_sigma, 1, 1);

    // means branch
    wprep_d_k<<<dim3(450), blk, 0, stream>>>(gm_w2, Wb, 192);
    deconv2_k<32,1,1,1><<<dim3(6,8,16), blk, 0, stream>>>(
        A1 + (size_t)3145728, 0, Wb, 0, gm_b2, gm_b2, gm_b2,
        A2, 0, nullptr, 192, 2, 2, 2);
    wprep_t_k<<<dim3(1350), blk, 0, stream>>>(gm_w3, Wb);
    conv3_k<<<dim3(2304, 1), blk, 0, stream>>>(
        A2, 0, Wb, 0, gm_b3, gm_b3, o_means, o_means, 0, 0);

    // weights branch
    wprep_d_k<<<dim3(1350), blk, 0, stream>>>(gw_w2, Wb, 576);
    deconv2_k<32,2,0,1><<<dim3(18,8,16), blk, 0, stream>>>(
        A1 + (size_t)2 * 3145728, 0, Wb, 0,
        gw_b2, gw_b2, gw_b2, nullptr, 0, MVp, 576, 0, 0, 0);
    head_k<<<dim3(16), blk, 0, stream>>>(MVp, gw_w3, gw_b3, o_w);
  }
}